// Round 4
// baseline (1754.551 us; speedup 1.0000x reference)
//
#include <hip/hip_runtime.h>
#include <math.h>

#define D 128
#define TILE 64
#define PADX 132   // xs row stride (floats); 528 B rows -> 16B aligned
#define PADW 68    // wsm row stride (floats); 272 B rows -> 16B aligned
#define ACCP 132   // acc_lds row stride (floats), aliases wsm (64*132 <= 128*68)

// ---------------- zero the stats block (512 floats) ----------------
__global__ void zero_stats_k(float* stats) {
    stats[blockIdx.x * blockDim.x + threadIdx.x] = 0.0f;
}

// ---------------- K1: fused node linear (U,V,B,C) ----------------
__global__ __launch_bounds__(256, 2)
void node_linear_k(const float* __restrict__ h_in,
                   const float* __restrict__ Uw, const float* __restrict__ Ub,
                   const float* __restrict__ Vw, const float* __restrict__ Vb,
                   const float* __restrict__ Bw, const float* __restrict__ Bb,
                   const float* __restrict__ Cw, const float* __restrict__ Cb,
                   float* __restrict__ outU, float* __restrict__ outV,
                   float* __restrict__ outB, float* __restrict__ outC,
                   int M)
{
    __shared__ float xs[TILE * PADX];
    __shared__ float wsm[D * PADW];
    const int tid = threadIdx.x;
    const int row0 = blockIdx.x * TILE;

    for (int f = tid; f < TILE * D / 4; f += 256) {
        int r = f >> 5, c4 = f & 31;
        int row = row0 + r;
        float4 v = make_float4(0.f, 0.f, 0.f, 0.f);
        if (row < M) v = *reinterpret_cast<const float4*>(h_in + (size_t)row * D + c4 * 4);
        *reinterpret_cast<float4*>(&xs[r * PADX + c4 * 4]) = v;
    }

    const int tx = tid & 31;
    const int ty = tid >> 5;

    const float* Ws[4] = {Uw, Vw, Bw, Cw};
    const float* Bs[4] = {Ub, Vb, Bb, Cb};
    float*       Os[4] = {outU, outV, outB, outC};

    #pragma unroll
    for (int wsel = 0; wsel < 4; ++wsel) {
        float acc[8][4];
        #pragma unroll
        for (int r = 0; r < 8; ++r)
            #pragma unroll
            for (int j = 0; j < 4; ++j) acc[r][j] = 0.f;

        const float* W = Ws[wsel];
        #pragma unroll
        for (int half = 0; half < 2; ++half) {
            __syncthreads();
            for (int f = tid; f < D * 64 / 4; f += 256) {
                int j = f >> 4, k4 = f & 15;
                float4 v = *reinterpret_cast<const float4*>(W + (size_t)j * D + half * 64 + k4 * 4);
                *reinterpret_cast<float4*>(&wsm[j * PADW + k4 * 4]) = v;
            }
            __syncthreads();
            #pragma unroll 4
            for (int k4 = 0; k4 < 16; ++k4) {
                float4 wv[4];
                #pragma unroll
                for (int jj = 0; jj < 4; ++jj)
                    wv[jj] = *reinterpret_cast<const float4*>(&wsm[(tx + 32 * jj) * PADW + k4 * 4]);
                #pragma unroll
                for (int r = 0; r < 8; ++r) {
                    float4 av = *reinterpret_cast<const float4*>(&xs[(ty * 8 + r) * PADX + half * 64 + k4 * 4]);
                    #pragma unroll
                    for (int jj = 0; jj < 4; ++jj)
                        acc[r][jj] += av.x * wv[jj].x + av.y * wv[jj].y + av.z * wv[jj].z + av.w * wv[jj].w;
                }
            }
        }
        const float* bias = Bs[wsel];
        float* O = Os[wsel];
        float bv[4];
        #pragma unroll
        for (int jj = 0; jj < 4; ++jj) bv[jj] = bias[tx + 32 * jj];
        #pragma unroll
        for (int r = 0; r < 8; ++r) {
            int row = row0 + ty * 8 + r;
            if (row < M) {
                #pragma unroll
                for (int jj = 0; jj < 4; ++jj)
                    O[(size_t)row * D + tx + 32 * jj] = acc[r][jj] + bv[jj];
            }
        }
    }
}

// ---------------- K2: fused edge kernel (early-gather version) ----------------
__global__ __launch_bounds__(256, 2)
void edge_k(const float* __restrict__ e_in,
            const int* __restrict__ eidx,   // [2][E] int32: dst then src
            const float* __restrict__ Aw, const float* __restrict__ Ab,
            const float* __restrict__ Vh, const float* __restrict__ Bh,
            const float* __restrict__ Ch,
            float* __restrict__ out_h, float* __restrict__ out_e,
            float* __restrict__ e_sum, float* __restrict__ e_sq,
            int E)
{
    __shared__ float xs[TILE * PADX];
    __shared__ float wsm[D * PADW];      // reused as acc_lds[64][ACCP] after GEMM
    __shared__ float sred[8][128];
    __shared__ float qred[8][128];

    const int tid = threadIdx.x;
    const int tx = tid & 31, ty = tid >> 5;
    const int e0 = blockIdx.x * TILE;

    // 1. edge indices for my 8 edges (clamped)
    int dn[8], sn[8], ev[8];
    #pragma unroll
    for (int r = 0; r < 8; ++r) {
        int e = e0 + ty * 8 + r;
        ev[r] = e;
        int ec = e < E ? e : E - 1;
        dn[r] = eidx[ec];
        sn[r] = eidx[(size_t)E + ec];
    }

    // 2. stage e_in tile
    for (int f = tid; f < TILE * D / 4; f += 256) {
        int r = f >> 5, c4 = f & 31;
        int row = e0 + r; if (row >= E) row = E - 1;
        *reinterpret_cast<float4*>(&xs[r * PADX + c4 * 4]) =
            *reinterpret_cast<const float4*>(e_in + (size_t)row * D + c4 * 4);
    }

    // 3. stage Aw half 0
    for (int f = tid; f < D * 64 / 4; f += 256) {
        int j = f >> 4, k4 = f & 15;
        *reinterpret_cast<float4*>(&wsm[j * PADW + k4 * 4]) =
            *reinterpret_cast<const float4*>(Aw + (size_t)j * D + k4 * 4);
    }

    // 4. issue ALL gathers now — they cannot sink past the barrier below,
    //    so their LLC latency hides under the GEMM k-loops.
    float4 gb[8], gc[8], gv[8];
    #pragma unroll
    for (int r = 0; r < 8; ++r) {
        gb[r] = *reinterpret_cast<const float4*>(Bh + (size_t)dn[r] * D + 4 * tx);
        gc[r] = *reinterpret_cast<const float4*>(Ch + (size_t)sn[r] * D + 4 * tx);
        gv[r] = *reinterpret_cast<const float4*>(Vh + (size_t)sn[r] * D + 4 * tx);
    }
    float4 bias4 = *reinterpret_cast<const float4*>(Ab + 4 * tx);

    float acc[8][4];
    #pragma unroll
    for (int r = 0; r < 8; ++r)
        #pragma unroll
        for (int j = 0; j < 4; ++j) acc[r][j] = 0.f;

    __syncthreads();
    // 5. k-loop half 0
    #pragma unroll 4
    for (int k4 = 0; k4 < 16; ++k4) {
        float4 wv[4];
        #pragma unroll
        for (int jj = 0; jj < 4; ++jj)
            wv[jj] = *reinterpret_cast<const float4*>(&wsm[(tx + 32 * jj) * PADW + k4 * 4]);
        #pragma unroll
        for (int r = 0; r < 8; ++r) {
            float4 av = *reinterpret_cast<const float4*>(&xs[(ty * 8 + r) * PADX + k4 * 4]);
            #pragma unroll
            for (int jj = 0; jj < 4; ++jj)
                acc[r][jj] += av.x * wv[jj].x + av.y * wv[jj].y + av.z * wv[jj].z + av.w * wv[jj].w;
        }
    }
    __syncthreads();
    // 6. stage Aw half 1
    for (int f = tid; f < D * 64 / 4; f += 256) {
        int j = f >> 4, k4 = f & 15;
        *reinterpret_cast<float4*>(&wsm[j * PADW + k4 * 4]) =
            *reinterpret_cast<const float4*>(Aw + (size_t)j * D + 64 + k4 * 4);
    }
    __syncthreads();
    // 7. k-loop half 1
    #pragma unroll 4
    for (int k4 = 0; k4 < 16; ++k4) {
        float4 wv[4];
        #pragma unroll
        for (int jj = 0; jj < 4; ++jj)
            wv[jj] = *reinterpret_cast<const float4*>(&wsm[(tx + 32 * jj) * PADW + k4 * 4]);
        #pragma unroll
        for (int r = 0; r < 8; ++r) {
            float4 av = *reinterpret_cast<const float4*>(&xs[(ty * 8 + r) * PADX + 64 + k4 * 4]);
            #pragma unroll
            for (int jj = 0; jj < 4; ++jj)
                acc[r][jj] += av.x * wv[jj].x + av.y * wv[jj].y + av.z * wv[jj].z + av.w * wv[jj].w;
        }
    }
    __syncthreads();

    // 8. transpose acc (cols tx+32*jj) -> acc_lds so each thread owns 4 contiguous cols
    float* acc_lds = wsm;
    #pragma unroll
    for (int r = 0; r < 8; ++r)
        #pragma unroll
        for (int jj = 0; jj < 4; ++jj)
            acc_lds[(ty * 8 + r) * ACCP + tx + 32 * jj] = acc[r][jj];
    __syncthreads();

    // 9. epilogue: combine, store out_e (float4), stats, gated-msg atomics
    float s0 = 0.f, s1 = 0.f, s2 = 0.f, s3 = 0.f;
    float q0 = 0.f, q1 = 0.f, q2 = 0.f, q3 = 0.f;
    #pragma unroll
    for (int r = 0; r < 8; ++r) {
        if (ev[r] < E) {
            float4 a4 = *reinterpret_cast<const float4*>(&acc_lds[(ty * 8 + r) * ACCP + 4 * tx]);
            float4 pre;
            pre.x = a4.x + bias4.x + gb[r].x + gc[r].x;
            pre.y = a4.y + bias4.y + gb[r].y + gc[r].y;
            pre.z = a4.z + bias4.z + gb[r].z + gc[r].z;
            pre.w = a4.w + bias4.w + gb[r].w + gc[r].w;
            *reinterpret_cast<float4*>(out_e + (size_t)ev[r] * D + 4 * tx) = pre;
            s0 += pre.x; q0 += pre.x * pre.x;
            s1 += pre.y; q1 += pre.y * pre.y;
            s2 += pre.z; q2 += pre.z * pre.z;
            s3 += pre.w; q3 += pre.w * pre.w;
            float4 ein = *reinterpret_cast<const float4*>(&xs[(ty * 8 + r) * PADX + 4 * tx]);
            float* dst = out_h + (size_t)dn[r] * D + 4 * tx;
            unsafeAtomicAdd(dst + 0, gv[r].x / (1.f + __expf(-ein.x)));
            unsafeAtomicAdd(dst + 1, gv[r].y / (1.f + __expf(-ein.y)));
            unsafeAtomicAdd(dst + 2, gv[r].z / (1.f + __expf(-ein.z)));
            unsafeAtomicAdd(dst + 3, gv[r].w / (1.f + __expf(-ein.w)));
        }
    }

    // 10. per-block stats reduction (cols 4*tx..4*tx+3, reduce over ty)
    *reinterpret_cast<float4*>(&sred[ty][4 * tx]) = make_float4(s0, s1, s2, s3);
    *reinterpret_cast<float4*>(&qred[ty][4 * tx]) = make_float4(q0, q1, q2, q3);
    __syncthreads();
    if (tid < 128) {
        float ss = 0.f, qq = 0.f;
        #pragma unroll
        for (int t = 0; t < 8; ++t) { ss += sred[t][tid]; qq += qred[t][tid]; }
        unsafeAtomicAdd(&e_sum[tid], ss);
        unsafeAtomicAdd(&e_sq[tid], qq);
    }
}

// ---------------- K3: column stats over a [rows x 128] matrix (float4) ----------------
__global__ void col_stats_k(const float* __restrict__ X, int rows,
                            float* __restrict__ sum, float* __restrict__ sumsq)
{
    __shared__ float sr[8][128], qr[8][128];
    const int tx = threadIdx.x & 31;
    const int rp = threadIdx.x >> 5;
    float4 s = make_float4(0.f, 0.f, 0.f, 0.f);
    float4 q = make_float4(0.f, 0.f, 0.f, 0.f);
    for (int r = blockIdx.x * 8 + rp; r < rows; r += gridDim.x * 8) {
        float4 v = *reinterpret_cast<const float4*>(X + (size_t)r * D + 4 * tx);
        s.x += v.x; q.x += v.x * v.x;
        s.y += v.y; q.y += v.y * v.y;
        s.z += v.z; q.z += v.z * v.z;
        s.w += v.w; q.w += v.w * v.w;
    }
    *reinterpret_cast<float4*>(&sr[rp][4 * tx]) = s;
    *reinterpret_cast<float4*>(&qr[rp][4 * tx]) = q;
    __syncthreads();
    if (threadIdx.x < 128) {
        float ss = 0.f, qq = 0.f;
        #pragma unroll
        for (int t = 0; t < 8; ++t) { ss += sr[t][threadIdx.x]; qq += qr[t][threadIdx.x]; }
        unsafeAtomicAdd(&sum[threadIdx.x], ss);
        unsafeAtomicAdd(&sumsq[threadIdx.x], qq);
    }
}

// ---------------- K4/K5: in-place BN + ReLU + residual (float4) ----------------
__global__ void finalize_k(const float* __restrict__ res_in,
                           float* __restrict__ out,
                           const float* __restrict__ sum, const float* __restrict__ sumsq,
                           const float* __restrict__ gamma, const float* __restrict__ beta,
                           float cntInv, int rows)
{
    const int tx = threadIdx.x & 31;
    const int rp = threadIdx.x >> 5;
    const int col4 = 4 * tx;
    float mu[4], g[4], b[4];
    #pragma unroll
    for (int i = 0; i < 4; ++i) {
        float m = sum[col4 + i] * cntInv;
        float var = sumsq[col4 + i] * cntInv - m * m;
        mu[i] = m;
        g[i] = gamma[col4 + i] * rsqrtf(var + 1e-5f);
        b[i] = beta[col4 + i];
    }
    for (int r = blockIdx.x * 8 + rp; r < rows; r += gridDim.x * 8) {
        size_t o = (size_t)r * D + col4;
        float4 x = *reinterpret_cast<const float4*>(out + o);
        float4 rr = *reinterpret_cast<const float4*>(res_in + o);
        float4 y;
        y.x = rr.x + fmaxf(g[0] * (x.x - mu[0]) + b[0], 0.f);
        y.y = rr.y + fmaxf(g[1] * (x.y - mu[1]) + b[1], 0.f);
        y.z = rr.z + fmaxf(g[2] * (x.z - mu[2]) + b[2], 0.f);
        y.w = rr.w + fmaxf(g[3] * (x.w - mu[3]) + b[3], 0.f);
        *reinterpret_cast<float4*>(out + o) = y;
    }
}

extern "C" void kernel_launch(void* const* d_in, const int* in_sizes, int n_in,
                              void* d_out, int out_size, void* d_ws, size_t ws_size,
                              hipStream_t stream)
{
    const float* h_in = (const float*)d_in[0];
    const float* e_in = (const float*)d_in[1];
    const int*   eidx = (const int*)d_in[2];
    const float* Uw = (const float*)d_in[3];  const float* Ub = (const float*)d_in[4];
    const float* Vw = (const float*)d_in[5];  const float* Vb = (const float*)d_in[6];
    const float* Aw = (const float*)d_in[7];  const float* Ab = (const float*)d_in[8];
    const float* Bw = (const float*)d_in[9];  const float* Bb = (const float*)d_in[10];
    const float* Cw = (const float*)d_in[11]; const float* Cb = (const float*)d_in[12];
    const float* hg = (const float*)d_in[13]; const float* hb = (const float*)d_in[14];
    const float* eg = (const float*)d_in[15]; const float* eb = (const float*)d_in[16];

    const int N = in_sizes[0] / D;
    const int E = in_sizes[1] / D;

    float* out_h = (float*)d_out;
    float* out_e = out_h + (size_t)N * D;

    float* ws = (float*)d_ws;
    float* Vh = ws;
    float* Bh = Vh + (size_t)N * D;
    float* Ch = Bh + (size_t)N * D;
    float* stats = Ch + (size_t)N * D;
    float* h_sum = stats;       float* h_sq = stats + 128;
    float* e_sum = stats + 256; float* e_sq = stats + 384;

    zero_stats_k<<<1, 512, 0, stream>>>(stats);
    node_linear_k<<<(N + TILE - 1) / TILE, 256, 0, stream>>>(
        h_in, Uw, Ub, Vw, Vb, Bw, Bb, Cw, Cb, out_h, Vh, Bh, Ch, N);
    edge_k<<<(E + TILE - 1) / TILE, 256, 0, stream>>>(
        e_in, eidx, Aw, Ab, Vh, Bh, Ch, out_h, out_e, e_sum, e_sq, E);
    col_stats_k<<<256, 256, 0, stream>>>(out_h, N, h_sum, h_sq);
    finalize_k<<<256, 256, 0, stream>>>(h_in, out_h, h_sum, h_sq, hg, hb, 1.0f / (float)N, N);
    finalize_k<<<2048, 256, 0, stream>>>(e_in, out_e, e_sum, e_sq, eg, eb, 1.0f / (float)E, E);
}

// Round 5
// 1112.425 us; speedup vs baseline: 1.5772x; 1.5772x over previous
//
#include <hip/hip_runtime.h>
#include <math.h>

#define D 128
#define TILE 64
#define PADX 132   // xs row stride (floats); 528 B rows -> 16B aligned
#define PADW 68    // wsm row stride (floats); 272 B rows -> 16B aligned
#define ACCP 132   // acc_lds row stride (floats), aliases wsm (64*132 <= 128*68)

// ---------------- zero the stats block (512 floats) ----------------
__global__ void zero_stats_k(float* stats) {
    stats[blockIdx.x * blockDim.x + threadIdx.x] = 0.0f;
}

// ---------------- K1: fused node linear (U,V,B,C) ----------------
__global__ __launch_bounds__(256, 2)
void node_linear_k(const float* __restrict__ h_in,
                   const float* __restrict__ Uw, const float* __restrict__ Ub,
                   const float* __restrict__ Vw, const float* __restrict__ Vb,
                   const float* __restrict__ Bw, const float* __restrict__ Bb,
                   const float* __restrict__ Cw, const float* __restrict__ Cb,
                   float* __restrict__ outU, float* __restrict__ outV,
                   float* __restrict__ outB, float* __restrict__ outC,
                   int M)
{
    __shared__ float xs[TILE * PADX];
    __shared__ float wsm[D * PADW];
    const int tid = threadIdx.x;
    const int row0 = blockIdx.x * TILE;

    for (int f = tid; f < TILE * D / 4; f += 256) {
        int r = f >> 5, c4 = f & 31;
        int row = row0 + r;
        float4 v = make_float4(0.f, 0.f, 0.f, 0.f);
        if (row < M) v = *reinterpret_cast<const float4*>(h_in + (size_t)row * D + c4 * 4);
        *reinterpret_cast<float4*>(&xs[r * PADX + c4 * 4]) = v;
    }

    const int tx = tid & 31;
    const int ty = tid >> 5;

    const float* Ws[4] = {Uw, Vw, Bw, Cw};
    const float* Bs[4] = {Ub, Vb, Bb, Cb};
    float*       Os[4] = {outU, outV, outB, outC};

    #pragma unroll
    for (int wsel = 0; wsel < 4; ++wsel) {
        float acc[8][4];
        #pragma unroll
        for (int r = 0; r < 8; ++r)
            #pragma unroll
            for (int j = 0; j < 4; ++j) acc[r][j] = 0.f;

        const float* W = Ws[wsel];
        #pragma unroll
        for (int half = 0; half < 2; ++half) {
            __syncthreads();
            for (int f = tid; f < D * 64 / 4; f += 256) {
                int j = f >> 4, k4 = f & 15;
                float4 v = *reinterpret_cast<const float4*>(W + (size_t)j * D + half * 64 + k4 * 4);
                *reinterpret_cast<float4*>(&wsm[j * PADW + k4 * 4]) = v;
            }
            __syncthreads();
            #pragma unroll 4
            for (int k4 = 0; k4 < 16; ++k4) {
                float4 wv[4];
                #pragma unroll
                for (int jj = 0; jj < 4; ++jj)
                    wv[jj] = *reinterpret_cast<const float4*>(&wsm[(tx + 32 * jj) * PADW + k4 * 4]);
                #pragma unroll
                for (int r = 0; r < 8; ++r) {
                    float4 av = *reinterpret_cast<const float4*>(&xs[(ty * 8 + r) * PADX + half * 64 + k4 * 4]);
                    #pragma unroll
                    for (int jj = 0; jj < 4; ++jj)
                        acc[r][jj] += av.x * wv[jj].x + av.y * wv[jj].y + av.z * wv[jj].z + av.w * wv[jj].w;
                }
            }
        }
        const float* bias = Bs[wsel];
        float* O = Os[wsel];
        float bv[4];
        #pragma unroll
        for (int jj = 0; jj < 4; ++jj) bv[jj] = bias[tx + 32 * jj];
        #pragma unroll
        for (int r = 0; r < 8; ++r) {
            int row = row0 + ty * 8 + r;
            if (row < M) {
                #pragma unroll
                for (int jj = 0; jj < 4; ++jj)
                    O[(size_t)row * D + tx + 32 * jj] = acc[r][jj] + bv[jj];
            }
        }
    }
}

// ---------------- K2: fused edge kernel ----------------
// Early float4 gathers hide LLC latency under the GEMM; messages go through
// LDS so the atomic instructions have lane-contiguous addresses (4x less
// fabric write traffic than per-thread float4-slice atomics).
__global__ __launch_bounds__(256, 2)
void edge_k(const float* __restrict__ e_in,
            const int* __restrict__ eidx,   // [2][E] int32: dst then src
            const float* __restrict__ Aw, const float* __restrict__ Ab,
            const float* __restrict__ Vh, const float* __restrict__ Bh,
            const float* __restrict__ Ch,
            float* __restrict__ out_h, float* __restrict__ out_e,
            float* __restrict__ e_sum, float* __restrict__ e_sq,
            int E)
{
    __shared__ float xs[TILE * PADX];
    __shared__ float wsm[D * PADW];      // reused as acc_lds[64][ACCP] after GEMM
    __shared__ float sred[8][128];
    __shared__ float qred[8][128];

    const int tid = threadIdx.x;
    const int tx = tid & 31, ty = tid >> 5;
    const int e0 = blockIdx.x * TILE;

    // 1. edge indices for my 8 edges (clamped)
    int dn[8], sn[8], ev[8];
    #pragma unroll
    for (int r = 0; r < 8; ++r) {
        int e = e0 + ty * 8 + r;
        ev[r] = e;
        int ec = e < E ? e : E - 1;
        dn[r] = eidx[ec];
        sn[r] = eidx[(size_t)E + ec];
    }

    // 2. stage e_in tile
    for (int f = tid; f < TILE * D / 4; f += 256) {
        int r = f >> 5, c4 = f & 31;
        int row = e0 + r; if (row >= E) row = E - 1;
        *reinterpret_cast<float4*>(&xs[r * PADX + c4 * 4]) =
            *reinterpret_cast<const float4*>(e_in + (size_t)row * D + c4 * 4);
    }

    // 3. stage Aw half 0
    for (int f = tid; f < D * 64 / 4; f += 256) {
        int j = f >> 4, k4 = f & 15;
        *reinterpret_cast<float4*>(&wsm[j * PADW + k4 * 4]) =
            *reinterpret_cast<const float4*>(Aw + (size_t)j * D + k4 * 4);
    }

    // 4. issue ALL gathers now — latency hides under the GEMM k-loops.
    float4 gb[8], gc[8], gv[8];
    #pragma unroll
    for (int r = 0; r < 8; ++r) {
        gb[r] = *reinterpret_cast<const float4*>(Bh + (size_t)dn[r] * D + 4 * tx);
        gc[r] = *reinterpret_cast<const float4*>(Ch + (size_t)sn[r] * D + 4 * tx);
        gv[r] = *reinterpret_cast<const float4*>(Vh + (size_t)sn[r] * D + 4 * tx);
    }
    float4 bias4 = *reinterpret_cast<const float4*>(Ab + 4 * tx);

    float acc[8][4];
    #pragma unroll
    for (int r = 0; r < 8; ++r)
        #pragma unroll
        for (int j = 0; j < 4; ++j) acc[r][j] = 0.f;

    __syncthreads();
    // 5. k-loop half 0
    #pragma unroll 4
    for (int k4 = 0; k4 < 16; ++k4) {
        float4 wv[4];
        #pragma unroll
        for (int jj = 0; jj < 4; ++jj)
            wv[jj] = *reinterpret_cast<const float4*>(&wsm[(tx + 32 * jj) * PADW + k4 * 4]);
        #pragma unroll
        for (int r = 0; r < 8; ++r) {
            float4 av = *reinterpret_cast<const float4*>(&xs[(ty * 8 + r) * PADX + k4 * 4]);
            #pragma unroll
            for (int jj = 0; jj < 4; ++jj)
                acc[r][jj] += av.x * wv[jj].x + av.y * wv[jj].y + av.z * wv[jj].z + av.w * wv[jj].w;
        }
    }
    __syncthreads();
    // 6. stage Aw half 1
    for (int f = tid; f < D * 64 / 4; f += 256) {
        int j = f >> 4, k4 = f & 15;
        *reinterpret_cast<float4*>(&wsm[j * PADW + k4 * 4]) =
            *reinterpret_cast<const float4*>(Aw + (size_t)j * D + 64 + k4 * 4);
    }
    __syncthreads();
    // 7. k-loop half 1
    #pragma unroll 4
    for (int k4 = 0; k4 < 16; ++k4) {
        float4 wv[4];
        #pragma unroll
        for (int jj = 0; jj < 4; ++jj)
            wv[jj] = *reinterpret_cast<const float4*>(&wsm[(tx + 32 * jj) * PADW + k4 * 4]);
        #pragma unroll
        for (int r = 0; r < 8; ++r) {
            float4 av = *reinterpret_cast<const float4*>(&xs[(ty * 8 + r) * PADX + 64 + k4 * 4]);
            #pragma unroll
            for (int jj = 0; jj < 4; ++jj)
                acc[r][jj] += av.x * wv[jj].x + av.y * wv[jj].y + av.z * wv[jj].z + av.w * wv[jj].w;
        }
    }
    __syncthreads();

    // 8. transpose acc (cols tx+32*jj) -> acc_lds so each thread owns 4 contiguous cols
    float* acc_lds = wsm;
    #pragma unroll
    for (int r = 0; r < 8; ++r)
        #pragma unroll
        for (int jj = 0; jj < 4; ++jj)
            acc_lds[(ty * 8 + r) * ACCP + tx + 32 * jj] = acc[r][jj];
    __syncthreads();

    // 9. epilogue: combine, store out_e (float4), stats; msg4 -> xs in-place
    float s0 = 0.f, s1 = 0.f, s2 = 0.f, s3 = 0.f;
    float q0 = 0.f, q1 = 0.f, q2 = 0.f, q3 = 0.f;
    #pragma unroll
    for (int r = 0; r < 8; ++r) {
        float4 ein = *reinterpret_cast<const float4*>(&xs[(ty * 8 + r) * PADX + 4 * tx]);
        float4 msg;
        msg.x = gv[r].x / (1.f + __expf(-ein.x));
        msg.y = gv[r].y / (1.f + __expf(-ein.y));
        msg.z = gv[r].z / (1.f + __expf(-ein.z));
        msg.w = gv[r].w / (1.f + __expf(-ein.w));
        if (ev[r] >= E) msg = make_float4(0.f, 0.f, 0.f, 0.f);
        if (ev[r] < E) {
            float4 a4 = *reinterpret_cast<const float4*>(&acc_lds[(ty * 8 + r) * ACCP + 4 * tx]);
            float4 pre;
            pre.x = a4.x + bias4.x + gb[r].x + gc[r].x;
            pre.y = a4.y + bias4.y + gb[r].y + gc[r].y;
            pre.z = a4.z + bias4.z + gb[r].z + gc[r].z;
            pre.w = a4.w + bias4.w + gb[r].w + gc[r].w;
            *reinterpret_cast<float4*>(out_e + (size_t)ev[r] * D + 4 * tx) = pre;
            s0 += pre.x; q0 += pre.x * pre.x;
            s1 += pre.y; q1 += pre.y * pre.y;
            s2 += pre.z; q2 += pre.z * pre.z;
            s3 += pre.w; q3 += pre.w * pre.w;
        }
        // overwrite my slice of xs with the gated message (each slice is
        // read only by this thread, so in-place is race-free)
        *reinterpret_cast<float4*>(&xs[(ty * 8 + r) * PADX + 4 * tx]) = msg;
    }
    __syncthreads();

    // 10. lane-contiguous atomics: col = tx + 32*jj, lanes cover 128 dwords densely
    #pragma unroll
    for (int r = 0; r < 8; ++r) {
        #pragma unroll
        for (int jj = 0; jj < 4; ++jj) {
            int col = tx + 32 * jj;
            float v = xs[(ty * 8 + r) * PADX + col];
            unsafeAtomicAdd(out_h + (size_t)dn[r] * D + col, v);
        }
    }

    // 11. per-block stats reduction
    *reinterpret_cast<float4*>(&sred[ty][4 * tx]) = make_float4(s0, s1, s2, s3);
    *reinterpret_cast<float4*>(&qred[ty][4 * tx]) = make_float4(q0, q1, q2, q3);
    __syncthreads();
    if (tid < 128) {
        float ss = 0.f, qq = 0.f;
        #pragma unroll
        for (int t = 0; t < 8; ++t) { ss += sred[t][tid]; qq += qred[t][tid]; }
        unsafeAtomicAdd(&e_sum[tid], ss);
        unsafeAtomicAdd(&e_sq[tid], qq);
    }
}

// ---------------- K3: column stats over a [rows x 128] matrix (float4) ----------------
__global__ void col_stats_k(const float* __restrict__ X, int rows,
                            float* __restrict__ sum, float* __restrict__ sumsq)
{
    __shared__ float sr[8][128], qr[8][128];
    const int tx = threadIdx.x & 31;
    const int rp = threadIdx.x >> 5;
    float4 s = make_float4(0.f, 0.f, 0.f, 0.f);
    float4 q = make_float4(0.f, 0.f, 0.f, 0.f);
    for (int r = blockIdx.x * 8 + rp; r < rows; r += gridDim.x * 8) {
        float4 v = *reinterpret_cast<const float4*>(X + (size_t)r * D + 4 * tx);
        s.x += v.x; q.x += v.x * v.x;
        s.y += v.y; q.y += v.y * v.y;
        s.z += v.z; q.z += v.z * v.z;
        s.w += v.w; q.w += v.w * v.w;
    }
    *reinterpret_cast<float4*>(&sr[rp][4 * tx]) = s;
    *reinterpret_cast<float4*>(&qr[rp][4 * tx]) = q;
    __syncthreads();
    if (threadIdx.x < 128) {
        float ss = 0.f, qq = 0.f;
        #pragma unroll
        for (int t = 0; t < 8; ++t) { ss += sr[t][threadIdx.x]; qq += qr[t][threadIdx.x]; }
        unsafeAtomicAdd(&sum[threadIdx.x], ss);
        unsafeAtomicAdd(&sumsq[threadIdx.x], qq);
    }
}

// ---------------- K4/K5: in-place BN + ReLU + residual (float4) ----------------
__global__ void finalize_k(const float* __restrict__ res_in,
                           float* __restrict__ out,
                           const float* __restrict__ sum, const float* __restrict__ sumsq,
                           const float* __restrict__ gamma, const float* __restrict__ beta,
                           float cntInv, int rows)
{
    const int tx = threadIdx.x & 31;
    const int rp = threadIdx.x >> 5;
    const int col4 = 4 * tx;
    float mu[4], g[4], b[4];
    #pragma unroll
    for (int i = 0; i < 4; ++i) {
        float m = sum[col4 + i] * cntInv;
        float var = sumsq[col4 + i] * cntInv - m * m;
        mu[i] = m;
        g[i] = gamma[col4 + i] * rsqrtf(var + 1e-5f);
        b[i] = beta[col4 + i];
    }
    for (int r = blockIdx.x * 8 + rp; r < rows; r += gridDim.x * 8) {
        size_t o = (size_t)r * D + col4;
        float4 x = *reinterpret_cast<const float4*>(out + o);
        float4 rr = *reinterpret_cast<const float4*>(res_in + o);
        float4 y;
        y.x = rr.x + fmaxf(g[0] * (x.x - mu[0]) + b[0], 0.f);
        y.y = rr.y + fmaxf(g[1] * (x.y - mu[1]) + b[1], 0.f);
        y.z = rr.z + fmaxf(g[2] * (x.z - mu[2]) + b[2], 0.f);
        y.w = rr.w + fmaxf(g[3] * (x.w - mu[3]) + b[3], 0.f);
        *reinterpret_cast<float4*>(out + o) = y;
    }
}

extern "C" void kernel_launch(void* const* d_in, const int* in_sizes, int n_in,
                              void* d_out, int out_size, void* d_ws, size_t ws_size,
                              hipStream_t stream)
{
    const float* h_in = (const float*)d_in[0];
    const float* e_in = (const float*)d_in[1];
    const int*   eidx = (const int*)d_in[2];
    const float* Uw = (const float*)d_in[3];  const float* Ub = (const float*)d_in[4];
    const float* Vw = (const float*)d_in[5];  const float* Vb = (const float*)d_in[6];
    const float* Aw = (const float*)d_in[7];  const float* Ab = (const float*)d_in[8];
    const float* Bw = (const float*)d_in[9];  const float* Bb = (const float*)d_in[10];
    const float* Cw = (const float*)d_in[11]; const float* Cb = (const float*)d_in[12];
    const float* hg = (const float*)d_in[13]; const float* hb = (const float*)d_in[14];
    const float* eg = (const float*)d_in[15]; const float* eb = (const float*)d_in[16];

    const int N = in_sizes[0] / D;
    const int E = in_sizes[1] / D;

    float* out_h = (float*)d_out;
    float* out_e = out_h + (size_t)N * D;

    float* ws = (float*)d_ws;
    float* Vh = ws;
    float* Bh = Vh + (size_t)N * D;
    float* Ch = Bh + (size_t)N * D;
    float* stats = Ch + (size_t)N * D;
    float* h_sum = stats;       float* h_sq = stats + 128;
    float* e_sum = stats + 256; float* e_sq = stats + 384;

    zero_stats_k<<<1, 512, 0, stream>>>(stats);
    node_linear_k<<<(N + TILE - 1) / TILE, 256, 0, stream>>>(
        h_in, Uw, Ub, Vw, Vb, Bw, Bb, Cw, Cb, out_h, Vh, Bh, Ch, N);
    edge_k<<<(E + TILE - 1) / TILE, 256, 0, stream>>>(
        e_in, eidx, Aw, Ab, Vh, Bh, Ch, out_h, out_e, e_sum, e_sq, E);
    col_stats_k<<<256, 256, 0, stream>>>(out_h, N, h_sum, h_sq);
    finalize_k<<<256, 256, 0, stream>>>(h_in, out_h, h_sum, h_sq, hg, hb, 1.0f / (float)N, N);
    finalize_k<<<2048, 256, 0, stream>>>(e_in, out_e, e_sum, e_sq, eg, eb, 1.0f / (float)E, E);
}

// Round 6
// 1077.406 us; speedup vs baseline: 1.6285x; 1.0325x over previous
//
#include <hip/hip_runtime.h>
#include <math.h>

#define D 128
#define TILE 64
#define PADX 132   // xs row stride (floats); 528 B rows -> 16B aligned
#define PADQ 36    // wq row stride (floats) for 32-float K-quarter rows

// ---------------- zero the stats block (512 floats) ----------------
__global__ void zero_stats_k(float* stats) {
    stats[blockIdx.x * blockDim.x + threadIdx.x] = 0.0f;
}

// ---------------- K1: fused node linear (U,V,B,C) ----------------
__global__ __launch_bounds__(256, 2)
void node_linear_k(const float* __restrict__ h_in,
                   const float* __restrict__ Uw, const float* __restrict__ Ub,
                   const float* __restrict__ Vw, const float* __restrict__ Vb,
                   const float* __restrict__ Bw, const float* __restrict__ Bb,
                   const float* __restrict__ Cw, const float* __restrict__ Cb,
                   float* __restrict__ outU, float* __restrict__ outV,
                   float* __restrict__ outB, float* __restrict__ outC,
                   int M)
{
    __shared__ float xs[TILE * PADX];
    __shared__ float wsm[D * 68];
    const int tid = threadIdx.x;
    const int row0 = blockIdx.x * TILE;

    for (int f = tid; f < TILE * D / 4; f += 256) {
        int r = f >> 5, c4 = f & 31;
        int row = row0 + r;
        float4 v = make_float4(0.f, 0.f, 0.f, 0.f);
        if (row < M) v = *reinterpret_cast<const float4*>(h_in + (size_t)row * D + c4 * 4);
        *reinterpret_cast<float4*>(&xs[r * PADX + c4 * 4]) = v;
    }

    const int tx = tid & 31;
    const int ty = tid >> 5;

    const float* Ws[4] = {Uw, Vw, Bw, Cw};
    const float* Bs[4] = {Ub, Vb, Bb, Cb};
    float*       Os[4] = {outU, outV, outB, outC};

    #pragma unroll
    for (int wsel = 0; wsel < 4; ++wsel) {
        float acc[8][4];
        #pragma unroll
        for (int r = 0; r < 8; ++r)
            #pragma unroll
            for (int j = 0; j < 4; ++j) acc[r][j] = 0.f;

        const float* W = Ws[wsel];
        #pragma unroll
        for (int half = 0; half < 2; ++half) {
            __syncthreads();
            for (int f = tid; f < D * 64 / 4; f += 256) {
                int j = f >> 4, k4 = f & 15;
                float4 v = *reinterpret_cast<const float4*>(W + (size_t)j * D + half * 64 + k4 * 4);
                *reinterpret_cast<float4*>(&wsm[j * 68 + k4 * 4]) = v;
            }
            __syncthreads();
            #pragma unroll 4
            for (int k4 = 0; k4 < 16; ++k4) {
                float4 wv[4];
                #pragma unroll
                for (int jj = 0; jj < 4; ++jj)
                    wv[jj] = *reinterpret_cast<const float4*>(&wsm[(tx + 32 * jj) * 68 + k4 * 4]);
                #pragma unroll
                for (int r = 0; r < 8; ++r) {
                    float4 av = *reinterpret_cast<const float4*>(&xs[(ty * 8 + r) * PADX + half * 64 + k4 * 4]);
                    #pragma unroll
                    for (int jj = 0; jj < 4; ++jj)
                        acc[r][jj] += av.x * wv[jj].x + av.y * wv[jj].y + av.z * wv[jj].z + av.w * wv[jj].w;
                }
            }
        }
        const float* bias = Bs[wsel];
        float* O = Os[wsel];
        float bv[4];
        #pragma unroll
        for (int jj = 0; jj < 4; ++jj) bv[jj] = bias[tx + 32 * jj];
        #pragma unroll
        for (int r = 0; r < 8; ++r) {
            int row = row0 + ty * 8 + r;
            if (row < M) {
                #pragma unroll
                for (int jj = 0; jj < 4; ++jj)
                    O[(size_t)row * D + tx + 32 * jj] = acc[r][jj] + bv[jj];
            }
        }
    }
}

// ---------------- K2: fused edge kernel ----------------
// Atomics (msg = sigmoid(e_in)*Vh[src]) are issued BEFORE the GEMM k-loops so
// the ~328 MB of fabric atomic traffic drains underneath the FMA work.
// LDS = 52.2 KB -> 3 blocks/CU for phase interleave across blocks.
__global__ __launch_bounds__(256, 3)
void edge_k(const float* __restrict__ e_in,
            const int* __restrict__ eidx,   // [2][E] int32: dst then src
            const float* __restrict__ Aw, const float* __restrict__ Ab,
            const float* __restrict__ Vh, const float* __restrict__ Bh,
            const float* __restrict__ Ch,
            float* __restrict__ out_h, float* __restrict__ out_e,
            float* __restrict__ e_sum, float* __restrict__ e_sq,
            int E)
{
    __shared__ float xs[TILE * PADX];   // e_in tile; reused as acc transpose buffer
    __shared__ float wq[D * PADQ];      // K-quarter of Aw; reused as stats scratch

    const int tid = threadIdx.x;
    const int tx = tid & 31, ty = tid >> 5;
    const int e0 = blockIdx.x * TILE;

    // 1. edge indices for my 8 edges (clamped)
    int dn[8], sn[8], ev[8];
    #pragma unroll
    for (int r = 0; r < 8; ++r) {
        int e = e0 + ty * 8 + r;
        ev[r] = e;
        int ec = e < E ? e : E - 1;
        dn[r] = eidx[ec];
        sn[r] = eidx[(size_t)E + ec];
    }

    // 2. stage e_in tile
    for (int f = tid; f < TILE * D / 4; f += 256) {
        int r = f >> 5, c4 = f & 31;
        int row = e0 + r; if (row >= E) row = E - 1;
        *reinterpret_cast<float4*>(&xs[r * PADX + c4 * 4]) =
            *reinterpret_cast<const float4*>(e_in + (size_t)row * D + c4 * 4);
    }
    // 3. stage Aw quarter 0
    for (int f = tid; f < D * 8; f += 256) {
        int j = f >> 3, k4 = f & 7;
        *reinterpret_cast<float4*>(&wq[j * PADQ + k4 * 4]) =
            *reinterpret_cast<const float4*>(Aw + (size_t)j * D + k4 * 4);
    }

    // 4. EARLY atomics: lane-contiguous col layout (col = tx + 32*jj).
    //    e_in rows are L2-hot (just staged); Vh rows come from L2/LLC.
    #pragma unroll
    for (int r = 0; r < 8; ++r) {
        if (ev[r] < E) {
            const float* er = e_in + (size_t)ev[r] * D;
            const float* vr = Vh + (size_t)sn[r] * D;
            float* dst = out_h + (size_t)dn[r] * D;
            #pragma unroll
            for (int jj = 0; jj < 4; ++jj) {
                int col = tx + 32 * jj;
                float m = vr[col] / (1.f + __expf(-er[col]));
                unsafeAtomicAdd(dst + col, m);
            }
        }
    }

    float acc[8][4];
    #pragma unroll
    for (int r = 0; r < 8; ++r)
        #pragma unroll
        for (int j = 0; j < 4; ++j) acc[r][j] = 0.f;

    // 5. K-quartered GEMM: acc[r][jj] += e_in_tile . Aw^T
    #pragma unroll
    for (int qtr = 0; ; ++qtr) {
        __syncthreads();   // wq (and xs on qtr 0) ready
        #pragma unroll 4
        for (int k4 = 0; k4 < 8; ++k4) {
            float4 wv[4];
            #pragma unroll
            for (int jj = 0; jj < 4; ++jj)
                wv[jj] = *reinterpret_cast<const float4*>(&wq[(tx + 32 * jj) * PADQ + k4 * 4]);
            #pragma unroll
            for (int r = 0; r < 8; ++r) {
                float4 av = *reinterpret_cast<const float4*>(&xs[(ty * 8 + r) * PADX + qtr * 32 + k4 * 4]);
                #pragma unroll
                for (int jj = 0; jj < 4; ++jj)
                    acc[r][jj] += av.x * wv[jj].x + av.y * wv[jj].y + av.z * wv[jj].z + av.w * wv[jj].w;
            }
        }
        if (qtr == 3) break;
        __syncthreads();   // all reads of wq done
        for (int f = tid; f < D * 8; f += 256) {
            int j = f >> 3, k4 = f & 7;
            *reinterpret_cast<float4*>(&wq[j * PADQ + k4 * 4]) =
                *reinterpret_cast<const float4*>(Aw + (size_t)j * D + (qtr + 1) * 32 + k4 * 4);
        }
    }
    __syncthreads();   // GEMM done; xs and wq free

    // 6. transpose acc through xs so each thread owns 4 contiguous cols
    #pragma unroll
    for (int r = 0; r < 8; ++r)
        #pragma unroll
        for (int jj = 0; jj < 4; ++jj)
            xs[(ty * 8 + r) * PADX + tx + 32 * jj] = acc[r][jj];
    __syncthreads();

    // 7. epilogue: gather Bh/Ch (float4), combine, store out_e, stats
    float4 bias4 = *reinterpret_cast<const float4*>(Ab + 4 * tx);
    float s0 = 0.f, s1 = 0.f, s2 = 0.f, s3 = 0.f;
    float q0 = 0.f, q1 = 0.f, q2 = 0.f, q3 = 0.f;
    #pragma unroll
    for (int r = 0; r < 8; ++r) {
        if (ev[r] < E) {
            float4 gb = *reinterpret_cast<const float4*>(Bh + (size_t)dn[r] * D + 4 * tx);
            float4 gc = *reinterpret_cast<const float4*>(Ch + (size_t)sn[r] * D + 4 * tx);
            float4 a4 = *reinterpret_cast<const float4*>(&xs[(ty * 8 + r) * PADX + 4 * tx]);
            float4 pre;
            pre.x = a4.x + bias4.x + gb.x + gc.x;
            pre.y = a4.y + bias4.y + gb.y + gc.y;
            pre.z = a4.z + bias4.z + gb.z + gc.z;
            pre.w = a4.w + bias4.w + gb.w + gc.w;
            *reinterpret_cast<float4*>(out_e + (size_t)ev[r] * D + 4 * tx) = pre;
            s0 += pre.x; q0 += pre.x * pre.x;
            s1 += pre.y; q1 += pre.y * pre.y;
            s2 += pre.z; q2 += pre.z * pre.z;
            s3 += pre.w; q3 += pre.w * pre.w;
        }
    }

    // 8. stats: lanes l and l^32 hold the same 4 cols -> shuffle-combine,
    //    then 4 per-wave partials through wq, one atomic per col per block.
    s0 += __shfl_xor(s0, 32); s1 += __shfl_xor(s1, 32);
    s2 += __shfl_xor(s2, 32); s3 += __shfl_xor(s3, 32);
    q0 += __shfl_xor(q0, 32); q1 += __shfl_xor(q1, 32);
    q2 += __shfl_xor(q2, 32); q3 += __shfl_xor(q3, 32);
    float* sbuf = wq;          // 4*128
    float* qbuf = wq + 512;    // 4*128
    if ((tid & 32) == 0) {
        int w = tid >> 6;
        *reinterpret_cast<float4*>(&sbuf[w * 128 + 4 * tx]) = make_float4(s0, s1, s2, s3);
        *reinterpret_cast<float4*>(&qbuf[w * 128 + 4 * tx]) = make_float4(q0, q1, q2, q3);
    }
    __syncthreads();
    if (tid < 128) {
        float ss = sbuf[tid] + sbuf[128 + tid] + sbuf[256 + tid] + sbuf[384 + tid];
        float qq = qbuf[tid] + qbuf[128 + tid] + qbuf[256 + tid] + qbuf[384 + tid];
        unsafeAtomicAdd(&e_sum[tid], ss);
        unsafeAtomicAdd(&e_sq[tid], qq);
    }
}

// ---------------- K3: column stats over a [rows x 128] matrix (float4) ----------------
__global__ void col_stats_k(const float* __restrict__ X, int rows,
                            float* __restrict__ sum, float* __restrict__ sumsq)
{
    __shared__ float sr[8][128], qr[8][128];
    const int tx = threadIdx.x & 31;
    const int rp = threadIdx.x >> 5;
    float4 s = make_float4(0.f, 0.f, 0.f, 0.f);
    float4 q = make_float4(0.f, 0.f, 0.f, 0.f);
    for (int r = blockIdx.x * 8 + rp; r < rows; r += gridDim.x * 8) {
        float4 v = *reinterpret_cast<const float4*>(X + (size_t)r * D + 4 * tx);
        s.x += v.x; q.x += v.x * v.x;
        s.y += v.y; q.y += v.y * v.y;
        s.z += v.z; q.z += v.z * v.z;
        s.w += v.w; q.w += v.w * v.w;
    }
    *reinterpret_cast<float4*>(&sr[rp][4 * tx]) = s;
    *reinterpret_cast<float4*>(&qr[rp][4 * tx]) = q;
    __syncthreads();
    if (threadIdx.x < 128) {
        float ss = 0.f, qq = 0.f;
        #pragma unroll
        for (int t = 0; t < 8; ++t) { ss += sr[t][threadIdx.x]; qq += qr[t][threadIdx.x]; }
        unsafeAtomicAdd(&sum[threadIdx.x], ss);
        unsafeAtomicAdd(&sumsq[threadIdx.x], qq);
    }
}

// ---------------- K4/K5: in-place BN + ReLU + residual (float4) ----------------
__global__ void finalize_k(const float* __restrict__ res_in,
                           float* __restrict__ out,
                           const float* __restrict__ sum, const float* __restrict__ sumsq,
                           const float* __restrict__ gamma, const float* __restrict__ beta,
                           float cntInv, int rows)
{
    const int tx = threadIdx.x & 31;
    const int rp = threadIdx.x >> 5;
    const int col4 = 4 * tx;
    float mu[4], g[4], b[4];
    #pragma unroll
    for (int i = 0; i < 4; ++i) {
        float m = sum[col4 + i] * cntInv;
        float var = sumsq[col4 + i] * cntInv - m * m;
        mu[i] = m;
        g[i] = gamma[col4 + i] * rsqrtf(var + 1e-5f);
        b[i] = beta[col4 + i];
    }
    for (int r = blockIdx.x * 8 + rp; r < rows; r += gridDim.x * 8) {
        size_t o = (size_t)r * D + col4;
        float4 x = *reinterpret_cast<const float4*>(out + o);
        float4 rr = *reinterpret_cast<const float4*>(res_in + o);
        float4 y;
        y.x = rr.x + fmaxf(g[0] * (x.x - mu[0]) + b[0], 0.f);
        y.y = rr.y + fmaxf(g[1] * (x.y - mu[1]) + b[1], 0.f);
        y.z = rr.z + fmaxf(g[2] * (x.z - mu[2]) + b[2], 0.f);
        y.w = rr.w + fmaxf(g[3] * (x.w - mu[3]) + b[3], 0.f);
        *reinterpret_cast<float4*>(out + o) = y;
    }
}

extern "C" void kernel_launch(void* const* d_in, const int* in_sizes, int n_in,
                              void* d_out, int out_size, void* d_ws, size_t ws_size,
                              hipStream_t stream)
{
    const float* h_in = (const float*)d_in[0];
    const float* e_in = (const float*)d_in[1];
    const int*   eidx = (const int*)d_in[2];
    const float* Uw = (const float*)d_in[3];  const float* Ub = (const float*)d_in[4];
    const float* Vw = (const float*)d_in[5];  const float* Vb = (const float*)d_in[6];
    const float* Aw = (const float*)d_in[7];  const float* Ab = (const float*)d_in[8];
    const float* Bw = (const float*)d_in[9];  const float* Bb = (const float*)d_in[10];
    const float* Cw = (const float*)d_in[11]; const float* Cb = (const float*)d_in[12];
    const float* hg = (const float*)d_in[13]; const float* hb = (const float*)d_in[14];
    const float* eg = (const float*)d_in[15]; const float* eb = (const float*)d_in[16];

    const int N = in_sizes[0] / D;
    const int E = in_sizes[1] / D;

    float* out_h = (float*)d_out;
    float* out_e = out_h + (size_t)N * D;

    float* ws = (float*)d_ws;
    float* Vh = ws;
    float* Bh = Vh + (size_t)N * D;
    float* Ch = Bh + (size_t)N * D;
    float* stats = Ch + (size_t)N * D;
    float* h_sum = stats;       float* h_sq = stats + 128;
    float* e_sum = stats + 256; float* e_sq = stats + 384;

    zero_stats_k<<<1, 512, 0, stream>>>(stats);
    node_linear_k<<<(N + TILE - 1) / TILE, 256, 0, stream>>>(
        h_in, Uw, Ub, Vw, Vb, Bw, Bb, Cw, Cb, out_h, Vh, Bh, Ch, N);
    edge_k<<<(E + TILE - 1) / TILE, 256, 0, stream>>>(
        e_in, eidx, Aw, Ab, Vh, Bh, Ch, out_h, out_e, e_sum, e_sq, E);
    col_stats_k<<<256, 256, 0, stream>>>(out_h, N, h_sum, h_sq);
    finalize_k<<<256, 256, 0, stream>>>(h_in, out_h, h_sum, h_sq, hg, hb, 1.0f / (float)N, N);
    finalize_k<<<2048, 256, 0, stream>>>(e_in, out_e, e_sum, e_sq, eg, eb, 1.0f / (float)E, E);
}